// Round 8
// baseline (123.133 us; speedup 1.0000x reference)
//
#include <hip/hip_runtime.h>
#include <hip/hip_bf16.h>

// PartitionedNormalization: per-domain BN stats (training mode) + affine.
// out[B][128] f32 = (gg+dg[s])*(x-mean[s])*rsqrt(var[s]+eps) + (gb+db[s])
//
// R8 theory: x (134MB) fits in 256MB L3. Non-temporal stores for out/partials
// keep x L3-resident across graph replays -> pass1 fetch collapses, apply
// becomes pure write-bound (~7 TB/s fill-proven path).

#define DIM 128
#define NDOM 8
#define PENT (NDOM + 2 * NDOM * DIM)  // 8 counts + 1024 sums + 1024 sqsums = 2056
#define EPSV 1e-3f
// per-wave LDS region (floats): [8 dom][64 lanes][4: smx,smy,sqx,sqy] + 8 cnt
#define WR 2056

typedef float __attribute__((ext_vector_type(4))) f32x4;

// ---------------- pass 1: wave-private LDS accumulation, b128 RMW ----------------
// One WAVE processes one row per iteration: 64 lanes x float2 = 128 cols.
// sum/sq interleaved in ONE 16B slot per lane -> 1 ds_read_b128 + 1 ds_write_b128
// per row. Lane addr = l*16 contiguous: conflict-free (m134).
// Wave-private regions + in-order per-wave DS pipe -> no atomics, no barriers.
__global__ __launch_bounds__(256, 4) void pn_reduce(const float2* __restrict__ x2,
                                                    const int* __restrict__ seg,
                                                    float* __restrict__ partials,
                                                    int rowsPerBlock) {
  __shared__ float acc[4 * WR];
  const int tid = threadIdx.x;
  const int w = tid >> 6;  // wave id 0..3
  const int l = tid & 63;  // lane id
  float* reg = acc + w * WR;

  for (int i = tid; i < 4 * WR; i += 256) acc[i] = 0.f;
  __syncthreads();

  const int rowsPerWave = rowsPerBlock >> 2;
  const int row0 = blockIdx.x * rowsPerBlock + w * rowsPerWave;

  for (int it = 0; it < rowsPerWave; it += 4) {
    const int4 sg = *(const int4*)(seg + row0 + it);  // 4 rows' domains (16B aligned)
    const float2 vA = x2[(size_t)(row0 + it + 0) * (DIM / 2) + l];
    const float2 vB = x2[(size_t)(row0 + it + 1) * (DIM / 2) + l];
    const float2 vC = x2[(size_t)(row0 + it + 2) * (DIM / 2) + l];
    const float2 vD = x2[(size_t)(row0 + it + 3) * (DIM / 2) + l];
#define RMW(S, V)                                            \
  {                                                          \
    float4* slot = (float4*)(reg + (S)*256 + l * 4);         \
    float4 o = *slot;                                        \
    o.x += (V).x;                                            \
    o.y += (V).y;                                            \
    o.z = fmaf((V).x, (V).x, o.z);                           \
    o.w = fmaf((V).y, (V).y, o.w);                           \
    *slot = o;                                               \
    if (l == 0) reg[2048 + (S)] += 1.f;                      \
  }
    RMW(sg.x, vA)
    RMW(sg.y, vB)
    RMW(sg.z, vC)
    RMW(sg.w, vD)
#undef RMW
  }
  __syncthreads();

  // combine the 4 wave regions -> partials[block][PENT] (counts | sums | sqs)
  // NT stores: partials is read once by reduce2; don't evict x from L3.
  float* outp = partials + (size_t)blockIdx.x * PENT;
  if (tid < NDOM) {
    float c = 0.f;
#pragma unroll
    for (int ww = 0; ww < 4; ++ww) c += acc[ww * WR + 2048 + tid];
    __builtin_nontemporal_store(c, &outp[tid]);
  }
  for (int i = tid; i < 2 * NDOM * DIM; i += 256) {
    const int isq = i >> 10;   // 0 = sum, 1 = sq
    const int j = i & 1023;    // (s, col)
    const int s = j >> 7;
    const int col = j & 127;
    const int off = s * 256 + (col >> 1) * 4 + isq * 2 + (col & 1);
    float v = 0.f;
#pragma unroll
    for (int ww = 0; ww < 4; ++ww) v += acc[ww * WR + off];
    __builtin_nontemporal_store(v, &outp[NDOM + i]);
  }
}

// ---------------- pass 2a: reduce NB partial rows -> 64 ----------------
__global__ __launch_bounds__(256) void pn_reduce2(const float* __restrict__ partials,
                                                  float* __restrict__ partials2,
                                                  int NB) {
  const int b = blockIdx.x;  // 0..63
  const int per = NB >> 6;   // NB is pow2 >= 64
  const int b0 = b * per;
  const int tid = threadIdx.x;
  float acc[9];
#pragma unroll
  for (int i = 0; i < 9; ++i) acc[i] = 0.f;
  for (int j = b0; j < b0 + per; ++j) {
    const float* p = partials + (size_t)j * PENT;
#pragma unroll
    for (int i = 0; i < 9; ++i) {
      const int e = tid + i * 256;
      if (e < PENT) acc[i] += __builtin_nontemporal_load(&p[e]);
    }
  }
  float* o = partials2 + (size_t)b * PENT;
#pragma unroll
  for (int i = 0; i < 9; ++i) {
    const int e = tid + i * 256;
    if (e < PENT) __builtin_nontemporal_store(acc[i], &o[e]);
  }
}

// ---------------- pass 2b: final reduce + scale/shift table ----------------
__global__ __launch_bounds__(1024) void pn_finalize(const float* __restrict__ partials2,
                                                    const float* __restrict__ gg,
                                                    const float* __restrict__ gb,
                                                    const float* __restrict__ dg,
                                                    const float* __restrict__ db,
                                                    float* __restrict__ stats) {
  __shared__ float cnt[NDOM];
  const int t = threadIdx.x;  // 0..1023 -> (k = t>>7, d = t&127)
  if (t < NDOM) {
    float c = 0.f;
    for (int j = 0; j < 64; ++j)
      c += __builtin_nontemporal_load(&partials2[(size_t)j * PENT + t]);
    cnt[t] = fmaxf(c, 1.f);
  }
  __syncthreads();
  float s = 0.f, q = 0.f;
  for (int j = 0; j < 64; ++j) {
    const float* p = partials2 + (size_t)j * PENT;
    s += __builtin_nontemporal_load(&p[NDOM + t]);
    q += __builtin_nontemporal_load(&p[NDOM + NDOM * DIM + t]);
  }
  const int k = t >> 7;
  const int d = t & (DIM - 1);
  const float n = cnt[k];
  const float mean = s / n;
  const float var = fmaxf(q / n - mean * mean, 0.f);
  const float rstd = rsqrtf(var + EPSV);
  const float scale = (gg[d] + dg[t]) * rstd;  // dg[k*128+d] == dg[t]
  const float shift = (gb[d] + db[t]) - scale * mean;
  stats[t] = scale;                 // temporal: read by every apply block
  stats[NDOM * DIM + t] = shift;
}

// ---------------- pass 3: normalize, NT store ----------------
__global__ __launch_bounds__(256) void pn_apply(const float* __restrict__ x,
                                                const int* __restrict__ seg,
                                                const float* __restrict__ stats,
                                                float* __restrict__ out) {
  const int g = blockIdx.x * 256 + threadIdx.x;  // float4 index
  const int row = g >> 5;                        // 32 float4 per row
  const int c4 = g & 31;
  const int s = seg[row];
  const float4 xv = ((const float4*)x)[g];       // temporal: keep x in L3
  const float4 a = ((const float4*)(stats + s * DIM))[c4];
  const float4 b = ((const float4*)(stats + NDOM * DIM + s * DIM))[c4];
  f32x4 o;
  o.x = fmaf(xv.x, a.x, b.x);
  o.y = fmaf(xv.y, a.y, b.y);
  o.z = fmaf(xv.z, a.z, b.z);
  o.w = fmaf(xv.w, a.w, b.w);
  // NT: out is never re-read; don't let 134MB of writes evict x from L3.
  __builtin_nontemporal_store(o, (f32x4*)out + g);
}

extern "C" void kernel_launch(void* const* d_in, const int* in_sizes, int n_in,
                              void* d_out, int out_size, void* d_ws, size_t ws_size,
                              hipStream_t stream) {
  const float* x = (const float*)d_in[0];
  const float* gg = (const float*)d_in[1];
  const float* gb = (const float*)d_in[2];
  const float* dg = (const float*)d_in[3];
  const float* db = (const float*)d_in[4];
  const int* seg = (const int*)d_in[5];
  float* out = (float*)d_out;

  const int B = in_sizes[5];  // 262144

  // workspace layout: partials[NB][2056] | partials2[64][2056] | stats[2048]
  int NB = 1024;  // exactly 4 blocks/CU, one dispatch round
  while (NB > 64 &&
         ((size_t)NB * PENT + 64 * PENT + 2 * NDOM * DIM) * sizeof(float) > ws_size)
    NB >>= 1;
  float* partials = (float*)d_ws;
  float* partials2 = partials + (size_t)NB * PENT;
  float* stats = partials2 + (size_t)64 * PENT;

  const int rpb = B / NB;  // 256; per wave 64 contiguous rows

  pn_reduce<<<NB, 256, 0, stream>>>((const float2*)x, seg, partials, rpb);
  pn_reduce2<<<64, 256, 0, stream>>>(partials, partials2, NB);
  pn_finalize<<<1, 1024, 0, stream>>>(partials2, gg, gb, dg, db, stats);

  const int nblk = (B * (DIM / 4)) / 256;  // 32768
  pn_apply<<<nblk, 256, 0, stream>>>(x, seg, stats, out);
}

// Round 10
// 101.007 us; speedup vs baseline: 1.2191x; 1.2191x over previous
//
#include <hip/hip_runtime.h>
#include <hip/hip_bf16.h>

// PartitionedNormalization: per-domain BN stats (training mode) + affine.
// out[B][128] f32 = (gg+dg[s])*(x-mean[s])*rsqrt(var[s]+eps) + (gb+db[s])
//
// R10: R9's row-pair collision path was compiler-merged (identical bodies,
// complementary exec masks -> one full-wave RMW, lost updates). Fix: 8
// HALF-WAVE-private LDS regions -> unconditional RMW, zero collision hazard.

#define DIM 128
#define NDOM 8
#define PENT (NDOM + 2 * NDOM * DIM)  // 8 counts + 1024 sums + 1024 sqsums = 2056
#define EPSV 1e-3f
#define WREG 2048  // per half-wave region (floats): sums[8][128] | sqs[8][128]

// ---------------- pass 1: half-wave-private LDS accumulation, float4 ----------------
// One WAVE processes a ROW PAIR per iteration step: lanes 0-31 = row r, lanes
// 32-63 = row r+1, float4/lane. Each HALF-WAVE owns a private 8KB LDS region:
// RMW is unconditional, race-free by construction. ds_read/write_b128 at
// lane-contiguous 16B slots: conflict-free (m134). No atomics, no branches.
__global__ __launch_bounds__(256) void pn_reduce(const float4* __restrict__ x4,
                                                 const int* __restrict__ seg,
                                                 float* __restrict__ partials,
                                                 int rowsPerBlock) {
  __shared__ float acc[8 * WREG];  // 64 KB -> 2 blocks/CU
  __shared__ float lcnt[NDOM];
  const int tid = threadIdx.x;
  const int w = tid >> 6;  // wave id 0..3
  const int l = tid & 63;  // lane id
  const int h = l >> 5;    // half-wave: 0 = first row of pair, 1 = second
  const int g = l & 31;    // float4 column group within row
  float* reg = acc + (w * 2 + h) * WREG;  // half-wave private

  for (int i = tid; i < 2 * WREG; i += 256) ((float4*)acc)[i] = make_float4(0.f, 0.f, 0.f, 0.f);
  if (tid < NDOM) lcnt[tid] = 0.f;
  __syncthreads();

  const int rowsPerWave = rowsPerBlock >> 2;  // 64
  const int row0 = blockIdx.x * rowsPerBlock + w * rowsPerWave;

#define RMW(S, V)                                    \
  {                                                  \
    float* bs = reg + (S) * 128 + g * 4;             \
    float* bq = bs + NDOM * DIM;                     \
    float4 os = *(float4*)bs;                        \
    float4 oq = *(float4*)bq;                        \
    os.x += (V).x;                                   \
    os.y += (V).y;                                   \
    os.z += (V).z;                                   \
    os.w += (V).w;                                   \
    oq.x = fmaf((V).x, (V).x, oq.x);                 \
    oq.y = fmaf((V).y, (V).y, oq.y);                 \
    oq.z = fmaf((V).z, (V).z, oq.z);                 \
    oq.w = fmaf((V).w, (V).w, oq.w);                 \
    *(float4*)bs = os;                               \
    *(float4*)bq = oq;                               \
  }

  for (int it = 0; it < rowsPerWave; it += 8) {
    const int r = row0 + it;
    const int4 sgA = *(const int4*)(seg + r);      // rows r..r+3
    const int4 sgB = *(const int4*)(seg + r + 4);  // rows r+4..r+7
    const float4 v0 = x4[(size_t)(r + 0 + h) * 32 + g];
    const float4 v1 = x4[(size_t)(r + 2 + h) * 32 + g];
    const float4 v2 = x4[(size_t)(r + 4 + h) * 32 + g];
    const float4 v3 = x4[(size_t)(r + 6 + h) * 32 + g];
    const int s0 = h ? sgA.y : sgA.x;
    const int s1 = h ? sgA.w : sgA.z;
    const int s2 = h ? sgB.y : sgB.x;
    const int s3 = h ? sgB.w : sgB.z;
    RMW(s0, v0)
    RMW(s1, v1)
    RMW(s2, v2)
    RMW(s3, v3)
  }
#undef RMW
  __syncthreads();

  // counts: block-level histogram of this block's seg rows (out of the hot loop)
  for (int i = tid; i < rowsPerBlock; i += 256)
    atomicAdd(&lcnt[seg[blockIdx.x * rowsPerBlock + i]], 1.f);
  __syncthreads();

  // flush: sum the 8 half-wave regions (layout: sums[0..1023] | sqs[1024..2047])
  float* outp = partials + (size_t)blockIdx.x * PENT;
  if (tid < NDOM) outp[tid] = lcnt[tid];
  for (int i = tid; i < 2 * NDOM * DIM; i += 256) {
    float v = 0.f;
#pragma unroll
    for (int rr = 0; rr < 8; ++rr) v += acc[rr * WREG + i];
    outp[NDOM + i] = v;
  }
}

// ---------------- pass 2a: reduce NB partial rows -> 64 ----------------
__global__ __launch_bounds__(256) void pn_reduce2(const float* __restrict__ partials,
                                                  float* __restrict__ partials2,
                                                  int NB) {
  const int b = blockIdx.x;  // 0..63
  const int per = NB >> 6;   // NB is pow2 >= 64
  const int b0 = b * per;
  const int tid = threadIdx.x;
  float acc[9];
#pragma unroll
  for (int i = 0; i < 9; ++i) acc[i] = 0.f;
  for (int j = b0; j < b0 + per; ++j) {
    const float* p = partials + (size_t)j * PENT;
#pragma unroll
    for (int i = 0; i < 9; ++i) {
      const int e = tid + i * 256;
      if (e < PENT) acc[i] += p[e];
    }
  }
  float* o = partials2 + (size_t)b * PENT;
#pragma unroll
  for (int i = 0; i < 9; ++i) {
    const int e = tid + i * 256;
    if (e < PENT) o[e] = acc[i];
  }
}

// ---------------- pass 2b: final reduce + scale/shift table (4 blocks) ----------------
__global__ __launch_bounds__(256) void pn_finalize(const float* __restrict__ partials2,
                                                   const float* __restrict__ gg,
                                                   const float* __restrict__ gb,
                                                   const float* __restrict__ dg,
                                                   const float* __restrict__ db,
                                                   float* __restrict__ stats) {
  const int t = blockIdx.x * 256 + threadIdx.x;  // 0..1023 -> (k = t>>7, d = t&127)
  const int k = t >> 7;
  const int d = t & (DIM - 1);
  float c = 0.f, s = 0.f, q = 0.f;
  for (int j = 0; j < 64; ++j) {
    const float* p = partials2 + (size_t)j * PENT;
    c += p[k];  // L1-broadcast across the wave
    s += p[NDOM + t];
    q += p[NDOM + NDOM * DIM + t];
  }
  const float n = fmaxf(c, 1.f);
  const float mean = s / n;
  const float var = fmaxf(q / n - mean * mean, 0.f);
  const float rstd = rsqrtf(var + EPSV);
  const float scale = (gg[d] + dg[t]) * rstd;  // dg[k*128+d] == dg[t]
  const float shift = (gb[d] + db[t]) - scale * mean;
  stats[t] = scale;
  stats[NDOM * DIM + t] = shift;
}

// ---------------- pass 3: normalize (at roofline; plain stores) ----------------
__global__ __launch_bounds__(256) void pn_apply(const float* __restrict__ x,
                                                const int* __restrict__ seg,
                                                const float* __restrict__ stats,
                                                float* __restrict__ out) {
  const int g = blockIdx.x * 256 + threadIdx.x;  // float4 index
  const int row = g >> 5;                        // 32 float4 per row
  const int c4 = g & 31;
  const int s = seg[row];
  const float4 xv = ((const float4*)x)[g];
  const float4 a = ((const float4*)(stats + s * DIM))[c4];
  const float4 b = ((const float4*)(stats + NDOM * DIM + s * DIM))[c4];
  float4 o;
  o.x = fmaf(xv.x, a.x, b.x);
  o.y = fmaf(xv.y, a.y, b.y);
  o.z = fmaf(xv.z, a.z, b.z);
  o.w = fmaf(xv.w, a.w, b.w);
  ((float4*)out)[g] = o;
}

extern "C" void kernel_launch(void* const* d_in, const int* in_sizes, int n_in,
                              void* d_out, int out_size, void* d_ws, size_t ws_size,
                              hipStream_t stream) {
  const float* x = (const float*)d_in[0];
  const float* gg = (const float*)d_in[1];
  const float* gb = (const float*)d_in[2];
  const float* dg = (const float*)d_in[3];
  const float* db = (const float*)d_in[4];
  const int* seg = (const int*)d_in[5];
  float* out = (float*)d_out;

  const int B = in_sizes[5];  // 262144

  // workspace layout: partials[NB][2056] | partials2[64][2056] | stats[2048]
  int NB = 1024;
  while (NB > 64 &&
         ((size_t)NB * PENT + 64 * PENT + 2 * NDOM * DIM) * sizeof(float) > ws_size)
    NB >>= 1;
  float* partials = (float*)d_ws;
  float* partials2 = partials + (size_t)NB * PENT;
  float* stats = partials2 + (size_t)64 * PENT;

  const int rpb = B / NB;  // 256; per wave 64 contiguous rows

  pn_reduce<<<NB, 256, 0, stream>>>((const float4*)x, seg, partials, rpb);
  pn_reduce2<<<64, 256, 0, stream>>>(partials, partials2, NB);
  pn_finalize<<<4, 256, 0, stream>>>(partials2, gg, gb, dg, db, stats);

  const int nblk = (B * (DIM / 4)) / 256;  // 32768
  pn_apply<<<nblk, 256, 0, stream>>>(x, seg, stats, out);
}